// Round 1
// baseline (273.961 us; speedup 1.0000x reference)
//
#include <hip/hip_runtime.h>

#define B_ 8
#define C_ 256
#define OC_ 128
#define L_ 4096
#define EPS_ 1e-5f
#define SPLITK 4

// ---------------- helpers ----------------
__device__ inline float blockReduceSum(float v, float* red, int nthreads) {
  int tid = threadIdx.x;
  red[tid] = v;
  __syncthreads();
  for (int s = nthreads >> 1; s > 0; s >>= 1) {
    if (tid < s) red[tid] += red[tid + s];
    __syncthreads();
  }
  float r = red[0];
  __syncthreads();
  return r;
}

// s[b,c] = sum_l x[b,c,l]   (grid: B*C blocks of 256)
__global__ __launch_bounds__(256) void k_rowsum(const float* __restrict__ x,
                                                float* __restrict__ s) {
  int row = blockIdx.x;  // b*C + c
  const float4* xr = (const float4*)(x + (size_t)row * L_);
  float acc = 0.f;
  for (int i = threadIdx.x; i < L_ / 4; i += 256) {
    float4 v = xr[i];
    acc += v.x + v.y + v.z + v.w;
  }
  __shared__ float red[256];
  float tot = blockReduceSum(acc, red, 256);
  if (threadIdx.x == 0) s[row] = tot;
}

// S[b] = X[b] X[b]^T, split-K partials. grid: (16, SPLITK, B), 256 thr.
__global__ __launch_bounds__(256) void k_xxt(const float* __restrict__ x,
                                             float* __restrict__ Spart) {
  const int b = blockIdx.z, split = blockIdx.y;
  const int ti = blockIdx.x >> 2, tj = blockIdx.x & 3;
  __shared__ float As[32][65], Bs[32][65];
  const float* Xb = x + (size_t)b * C_ * L_;
  const int k0 = split * (L_ / SPLITK);
  float acc[4][4] = {};
  const int tk = threadIdx.x & 31, trow = threadIdx.x >> 5;
  const int tx = threadIdx.x & 15, ty = threadIdx.x >> 4;
  for (int kt = 0; kt < L_ / SPLITK; kt += 32) {
#pragma unroll
    for (int r = 0; r < 64; r += 8) {
      As[tk][r + trow] = Xb[(size_t)(ti * 64 + r + trow) * L_ + k0 + kt + tk];
      Bs[tk][r + trow] = Xb[(size_t)(tj * 64 + r + trow) * L_ + k0 + kt + tk];
    }
    __syncthreads();
#pragma unroll
    for (int kk = 0; kk < 32; kk++) {
      float a[4], bv[4];
#pragma unroll
      for (int i = 0; i < 4; i++) a[i] = As[kk][ty * 4 + i];
#pragma unroll
      for (int j = 0; j < 4; j++) bv[j] = Bs[kk][tx * 4 + j];
#pragma unroll
      for (int i = 0; i < 4; i++)
#pragma unroll
        for (int j = 0; j < 4; j++) acc[i][j] += a[i] * bv[j];
    }
    __syncthreads();
  }
  float* Sp = Spart + ((size_t)split * B_ + b) * C_ * C_;
#pragma unroll
  for (int i = 0; i < 4; i++)
#pragma unroll
    for (int j = 0; j < 4; j++)
      Sp[(size_t)(ti * 64 + ty * 4 + i) * C_ + tj * 64 + tx * 4 + j] = acc[i][j];
}

// S = sum over splits of Spart. grid: B*C*C/256.
__global__ __launch_bounds__(256) void k_sreduce(const float* __restrict__ Spart,
                                                 float* __restrict__ S) {
  size_t idx = (size_t)blockIdx.x * 256 + threadIdx.x;
  float acc = 0.f;
  for (int sp = 0; sp < SPLITK; sp++) acc += Spart[(size_t)sp * B_ * C_ * C_ + idx];
  S[idx] = acc;
}

// ps[b,o]=phi_w[o,:].s[b]; gs[b,o]=g_w[o,:].s[b]   grid: B, 256 thr
__global__ __launch_bounds__(256) void k_psgs(const float* __restrict__ s,
                                              const float* __restrict__ phi_w,
                                              const float* __restrict__ g_w,
                                              float* __restrict__ ps,
                                              float* __restrict__ gs) {
  int b = blockIdx.x;
  __shared__ float sl[C_];
  sl[threadIdx.x] = s[b * C_ + threadIdx.x];
  __syncthreads();
  int o = threadIdx.x & 127;
  const float* w = (threadIdx.x < 128) ? phi_w : g_w;
  float acc = 0.f;
  for (int c = 0; c < C_; c++) acc += w[o * C_ + c] * sl[c];
  if (threadIdx.x < 128) ps[b * OC_ + o] = acc;
  else                   gs[b * OC_ + o] = acc;
}

// T1[b,o,:] = phi_w[o,:] @ S[b]   grid: B*OC, 256 thr
__global__ __launch_bounds__(256) void k_t1(const float* __restrict__ S,
                                            const float* __restrict__ phi_w,
                                            float* __restrict__ T1) {
  int b = blockIdx.x >> 7, o = blockIdx.x & 127;
  __shared__ float pw[C_];
  pw[threadIdx.x] = phi_w[o * C_ + threadIdx.x];
  __syncthreads();
  const float* Sb = S + (size_t)b * C_ * C_;
  float acc = 0.f;
  for (int c = 0; c < C_; c++) acc += pw[c] * Sb[(size_t)c * C_ + threadIdx.x];
  T1[((size_t)b * OC_ + o) * C_ + threadIdx.x] = acc;
}

// M[b,op,o] = T1[b,op,:].g_w[o,:] + rank-1 terms    grid: B*OC, 128 thr
__global__ __launch_bounds__(128) void k_m(const float* __restrict__ T1,
                                           const float* __restrict__ g_w,
                                           const float* __restrict__ phi_b,
                                           const float* __restrict__ g_b,
                                           const float* __restrict__ ps,
                                           const float* __restrict__ gs,
                                           float* __restrict__ M) {
  int b = blockIdx.x >> 7, op = blockIdx.x & 127;
  __shared__ float t1[C_];
  t1[threadIdx.x] = T1[((size_t)b * OC_ + op) * C_ + threadIdx.x];
  t1[threadIdx.x + 128] = T1[((size_t)b * OC_ + op) * C_ + threadIdx.x + 128];
  __syncthreads();
  int o = threadIdx.x;
  float acc = 0.f;
  for (int c = 0; c < C_; c++) acc += t1[c] * g_w[o * C_ + c];
  acc += phi_b[op] * gs[b * OC_ + o] + ps[b * OC_ + op] * g_b[o] +
         (float)L_ * phi_b[op] * g_b[o];
  M[((size_t)b * OC_ + op) * OC_ + o] = acc;
}

// U[b,c,op] = (W_w[c,:].M[b,op,:])/L ; q[b,c] = U.theta_b + W_b  grid: B*C, 128 thr
__global__ __launch_bounds__(128) void k_uq(const float* __restrict__ M,
                                            const float* __restrict__ W_w,
                                            const float* __restrict__ theta_b,
                                            const float* __restrict__ W_b,
                                            float* __restrict__ U,
                                            float* __restrict__ q) {
  int b = blockIdx.x >> 8, c = blockIdx.x & 255;
  __shared__ float wr[OC_];
  wr[threadIdx.x] = W_w[c * OC_ + threadIdx.x];
  __syncthreads();
  int op = threadIdx.x;
  const float* Mb = M + (size_t)b * OC_ * OC_;
  float acc = 0.f;
  for (int o = 0; o < OC_; o++) acc += wr[o] * Mb[(size_t)op * OC_ + o];
  acc *= (1.0f / (float)L_);
  U[((size_t)b * C_ + c) * OC_ + op] = acc;
  __shared__ float red[OC_];
  float tot = blockReduceSum(acc * theta_b[op], red, OC_);
  if (threadIdx.x == 0) q[b * C_ + c] = tot + W_b[c];
}

// Q[b,c,:] = U[b,c,:] @ theta_w    grid: B*C, 256 thr
__global__ __launch_bounds__(256) void k_q(const float* __restrict__ U,
                                           const float* __restrict__ theta_w,
                                           float* __restrict__ Q) {
  int b = blockIdx.x >> 8, c = blockIdx.x & 255;
  __shared__ float u[OC_];
  if (threadIdx.x < OC_) u[threadIdx.x] = U[((size_t)b * C_ + c) * OC_ + threadIdx.x];
  __syncthreads();
  float acc = 0.f;
  for (int op = 0; op < OC_; op++) acc += u[op] * theta_w[(size_t)op * C_ + threadIdx.x];
  Q[((size_t)b * C_ + c) * C_ + threadIdx.x] = acc;
}

// BN partial stats from S,s:  sum1=Qs+L*q, sum2=diag(QSQ^T)+2q(Qs)+Lq^2. grid: B*C, 256 thr
__global__ __launch_bounds__(256) void k_stats(const float* __restrict__ Q,
                                               const float* __restrict__ S,
                                               const float* __restrict__ s,
                                               const float* __restrict__ q,
                                               float* __restrict__ sum1,
                                               float* __restrict__ sum2) {
  int b = blockIdx.x >> 8, c = blockIdx.x & 255;
  __shared__ float qrow[C_];
  qrow[threadIdx.x] = Q[((size_t)b * C_ + c) * C_ + threadIdx.x];
  __syncthreads();
  const float* Sb = S + (size_t)b * C_ * C_;
  float r = 0.f;
  for (int cp = 0; cp < C_; cp++) r += qrow[cp] * Sb[(size_t)cp * C_ + threadIdx.x];
  __shared__ float red[C_];
  float e2 = blockReduceSum(r * qrow[threadIdx.x], red, C_);
  float qs = blockReduceSum(qrow[threadIdx.x] * s[b * C_ + threadIdx.x], red, C_);
  if (threadIdx.x == 0) {
    float qv = q[b * C_ + c];
    sum1[b * C_ + c] = qs + (float)L_ * qv;
    sum2[b * C_ + c] = e2 + 2.f * qv * qs + (float)L_ * qv * qv;
  }
}

// Fold BN + residual into Q'' and q'. grid: B*C, 256 thr
__global__ __launch_bounds__(256) void k_build(const float* __restrict__ Q,
                                               const float* __restrict__ q,
                                               const float* __restrict__ sum1,
                                               const float* __restrict__ sum2,
                                               const float* __restrict__ gamma,
                                               const float* __restrict__ beta,
                                               float* __restrict__ Qpp,
                                               float* __restrict__ qp) {
  int b = blockIdx.x >> 8, c = blockIdx.x & 255;
  float m = 0.f, e = 0.f;
  for (int bb = 0; bb < B_; bb++) {
    m += sum1[bb * C_ + c];
    e += sum2[bb * C_ + c];
  }
  const float inv_n = 1.f / (float)(B_ * L_);
  m *= inv_n;
  e *= inv_n;
  float var = e - m * m;
  float gsc = gamma[c] * rsqrtf(var + EPS_);
  size_t base = ((size_t)b * C_ + c) * C_;
  Qpp[base + threadIdx.x] = gsc * Q[base + threadIdx.x] + (threadIdx.x == (unsigned)c ? 1.f : 0.f);
  if (threadIdx.x == 0) qp[b * C_ + c] = gsc * (q[b * C_ + c] - m) + beta[c];
}

// out[b] = Qpp[b] @ X[b] + qp[b]. grid: (L/64, C/64, B), 256 thr
__global__ __launch_bounds__(256) void k_out(const float* __restrict__ Qpp,
                                             const float* __restrict__ qp,
                                             const float* __restrict__ x,
                                             float* __restrict__ out) {
  const int b = blockIdx.z, ct = blockIdx.y, lt = blockIdx.x;
  __shared__ float As[32][65], Bs[32][65];
  const float* Ab = Qpp + (size_t)b * C_ * C_;
  const float* Xb = x + (size_t)b * C_ * L_;
  float acc[4][4] = {};
  const int tkA = threadIdx.x & 31, trA = threadIdx.x >> 5;
  const int tnB = threadIdx.x & 63, tkB = threadIdx.x >> 6;
  const int tx = threadIdx.x & 15, ty = threadIdx.x >> 4;
  for (int k0 = 0; k0 < C_; k0 += 32) {
#pragma unroll
    for (int r = 0; r < 64; r += 8)
      As[tkA][r + trA] = Ab[(size_t)(ct * 64 + r + trA) * C_ + k0 + tkA];
#pragma unroll
    for (int r = 0; r < 32; r += 4)
      Bs[r + tkB][tnB] = Xb[(size_t)(k0 + r + tkB) * L_ + lt * 64 + tnB];
    __syncthreads();
#pragma unroll
    for (int kk = 0; kk < 32; kk++) {
      float a[4], bv[4];
#pragma unroll
      for (int i = 0; i < 4; i++) a[i] = As[kk][ty * 4 + i];
#pragma unroll
      for (int j = 0; j < 4; j++) bv[j] = Bs[kk][tx * 4 + j];
#pragma unroll
      for (int i = 0; i < 4; i++)
#pragma unroll
        for (int j = 0; j < 4; j++) acc[i][j] += a[i] * bv[j];
    }
    __syncthreads();
  }
#pragma unroll
  for (int i = 0; i < 4; i++) {
    float qv = qp[b * C_ + ct * 64 + ty * 4 + i];
#pragma unroll
    for (int j = 0; j < 4; j++)
      out[((size_t)b * C_ + ct * 64 + ty * 4 + i) * L_ + lt * 64 + tx * 4 + j] =
          acc[i][j] + qv;
  }
}

extern "C" void kernel_launch(void* const* d_in, const int* in_sizes, int n_in,
                              void* d_out, int out_size, void* d_ws, size_t ws_size,
                              hipStream_t stream) {
  const float* x       = (const float*)d_in[0];
  const float* g_w     = (const float*)d_in[1];
  const float* g_b     = (const float*)d_in[2];
  const float* theta_w = (const float*)d_in[3];
  const float* theta_b = (const float*)d_in[4];
  const float* phi_w   = (const float*)d_in[5];
  const float* phi_b   = (const float*)d_in[6];
  const float* W_w     = (const float*)d_in[7];
  const float* W_b     = (const float*)d_in[8];
  const float* gamma   = (const float*)d_in[9];
  const float* beta    = (const float*)d_in[10];
  float* out = (float*)d_out;

  float* ws = (float*)d_ws;
  size_t off = 0;
  float* Spart = ws + off; off += (size_t)SPLITK * B_ * C_ * C_;  // 2M
  float* S     = ws + off; off += (size_t)B_ * C_ * C_;           // 512K
  float* s_    = ws + off; off += B_ * C_;
  float* ps    = ws + off; off += B_ * OC_;
  float* gs    = ws + off; off += B_ * OC_;
  float* T1    = ws + off; off += (size_t)B_ * OC_ * C_;
  float* M     = ws + off; off += (size_t)B_ * OC_ * OC_;
  float* U     = ws + off; off += (size_t)B_ * C_ * OC_;
  float* qv    = ws + off; off += B_ * C_;
  float* Q     = ws + off; off += (size_t)B_ * C_ * C_;
  float* sum1  = ws + off; off += B_ * C_;
  float* sum2  = ws + off; off += B_ * C_;
  float* Qpp   = ws + off; off += (size_t)B_ * C_ * C_;
  float* qp    = ws + off; off += B_ * C_;

  k_rowsum<<<B_ * C_, 256, 0, stream>>>(x, s_);
  k_xxt<<<dim3(16, SPLITK, B_), 256, 0, stream>>>(x, Spart);
  k_sreduce<<<(B_ * C_ * C_) / 256, 256, 0, stream>>>(Spart, S);
  k_psgs<<<B_, 256, 0, stream>>>(s_, phi_w, g_w, ps, gs);
  k_t1<<<B_ * OC_, 256, 0, stream>>>(S, phi_w, T1);
  k_m<<<B_ * OC_, 128, 0, stream>>>(T1, g_w, phi_b, g_b, ps, gs, M);
  k_uq<<<B_ * C_, 128, 0, stream>>>(M, W_w, theta_b, W_b, U, qv);
  k_q<<<B_ * C_, 256, 0, stream>>>(U, theta_w, Q);
  k_stats<<<B_ * C_, 256, 0, stream>>>(Q, S, s_, qv, sum1, sum2);
  k_build<<<B_ * C_, 256, 0, stream>>>(Q, qv, sum1, sum2, gamma, beta, Qpp, qp);
  k_out<<<dim3(L_ / 64, C_ / 64, B_), 256, 0, stream>>>(Qpp, qp, x, out);
}

// Round 2
// 157.592 us; speedup vs baseline: 1.7384x; 1.7384x over previous
//
#include <hip/hip_runtime.h>
#include <hip/hip_bf16.h>

#define B_ 8
#define C_ 256
#define OC_ 128
#define L_ 4096
#define EPS_ 1e-5f
#define SPLITK 8

typedef unsigned short u16;
typedef __attribute__((ext_vector_type(4))) unsigned short u16x4;
typedef __attribute__((ext_vector_type(4))) float f32x4;
typedef __attribute__((ext_vector_type(8))) short bf16x8;

__device__ inline u16 f2bf(float f) {
  union { __hip_bfloat16 h; u16 u; } v;
  v.h = __float2bfloat16(f);
  return v.u;
}

__device__ inline void gload_lds16(const void* g, void* lds) {
  __builtin_amdgcn_global_load_lds(
      (const __attribute__((address_space(1))) unsigned int*)g,
      (__attribute__((address_space(3))) unsigned int*)lds, 16, 0, 0);
}

// ---------------- helpers ----------------
__device__ inline float blockReduceSum(float v, float* red, int nthreads) {
  int tid = threadIdx.x;
  red[tid] = v;
  __syncthreads();
  for (int s = nthreads >> 1; s > 0; s >>= 1) {
    if (tid < s) red[tid] += red[tid + s];
    __syncthreads();
  }
  float r = red[0];
  __syncthreads();
  return r;
}

// Convert x -> bf16 in both layouts: Xb[b][c][l], XbT[b][l][c]
__global__ __launch_bounds__(256) void k_cvt(const float* __restrict__ x,
                                             u16* __restrict__ Xb,
                                             u16* __restrict__ XbT) {
  __shared__ u16 T[64][72];
  const int b = blockIdx.z, c0 = blockIdx.y * 64, l0 = blockIdx.x * 64;
  const int tid = threadIdx.x;
#pragma unroll
  for (int it = 0; it < 4; ++it) {
    int idx = it * 256 + tid;
    int row = idx >> 4;          // c within tile
    int col = (idx & 15) << 2;   // l within tile
    size_t gi = ((size_t)(b * C_ + c0 + row)) * L_ + l0 + col;
    float4 v = *(const float4*)(x + gi);
    u16 u0 = f2bf(v.x), u1 = f2bf(v.y), u2 = f2bf(v.z), u3 = f2bf(v.w);
    u16x4 u = {u0, u1, u2, u3};
    *(u16x4*)(Xb + gi) = u;
    T[row][col] = u0; T[row][col + 1] = u1; T[row][col + 2] = u2; T[row][col + 3] = u3;
  }
  __syncthreads();
#pragma unroll
  for (int it = 0; it < 4; ++it) {
    int idx = it * 256 + tid;
    int lrow = idx >> 4;
    int ccol = (idx & 15) << 2;
    u16x4 u = {T[ccol][lrow], T[ccol + 1][lrow], T[ccol + 2][lrow], T[ccol + 3][lrow]};
    *(u16x4*)(XbT + ((size_t)b * L_ + l0 + lrow) * C_ + c0 + ccol) = u;
  }
}

// s[b,c] = sum_l x[b,c,l]
__global__ __launch_bounds__(256) void k_rowsum(const float* __restrict__ x,
                                                float* __restrict__ s) {
  int row = blockIdx.x;  // b*C + c
  const float4* xr = (const float4*)(x + (size_t)row * L_);
  float acc = 0.f;
  for (int i = threadIdx.x; i < L_ / 4; i += 256) {
    float4 v = xr[i];
    acc += v.x + v.y + v.z + v.w;
  }
  __shared__ float red[256];
  float tot = blockReduceSum(acc, red, 256);
  if (threadIdx.x == 0) s[row] = tot;
}

// S[b] = Xb Xb^T via MFMA bf16, split-K. grid: (4, SPLITK, B), 256 thr (4 waves).
__global__ __launch_bounds__(256) void k_xxt(const u16* __restrict__ Xb,
                                             float* __restrict__ Spart) {
  const int b = blockIdx.z, split = blockIdx.y;
  const int ti = blockIdx.x >> 1, tj = blockIdx.x & 1;
  __shared__ u16 lds[2 * 128 * 64];  // A tile 16KB + B tile 16KB, XOR-swizzled
  const int tid = threadIdx.x, lane = tid & 63;
  const int wid = tid >> 6, wr = wid >> 1, wc = wid & 1;
  const u16* Arows = Xb + ((size_t)b * C_ + ti * 128) * L_;
  const u16* Brows = Xb + ((size_t)b * C_ + tj * 128) * L_;
  const int k0 = split * (L_ / SPLITK);
  f32x4 acc[4][4] = {};
  for (int kt = 0; kt < L_ / SPLITK; kt += 64) {
    __syncthreads();
#pragma unroll
    for (int ch = 0; ch < 4; ch++) {
      int d = ch * 4096 + tid * 16;             // linear dest byte in tile
      int row = d >> 7;                          // 128B per row
      int kb = (d & 127) ^ ((row & 7) << 4);     // inverse-swizzled source kbyte
      gload_lds16(Arows + (size_t)row * L_ + k0 + kt + (kb >> 1), (char*)lds + d);
      gload_lds16(Brows + (size_t)row * L_ + k0 + kt + (kb >> 1), (char*)lds + 16384 + d);
    }
    asm volatile("s_waitcnt vmcnt(0)" ::: "memory");
    __syncthreads();
#pragma unroll
    for (int ks = 0; ks < 2; ks++) {
      bf16x8 af[4], bfr[4];
#pragma unroll
      for (int m = 0; m < 4; m++) {
        int row = wr * 64 + m * 16 + (lane & 15);
        int kb = ((ks << 6) + ((lane >> 4) << 4)) ^ ((row & 7) << 4);
        af[m] = *(const bf16x8*)((const char*)lds + row * 128 + kb);
      }
#pragma unroll
      for (int n = 0; n < 4; n++) {
        int row = wc * 64 + n * 16 + (lane & 15);
        int kb = ((ks << 6) + ((lane >> 4) << 4)) ^ ((row & 7) << 4);
        bfr[n] = *(const bf16x8*)((const char*)lds + 16384 + row * 128 + kb);
      }
#pragma unroll
      for (int m = 0; m < 4; m++)
#pragma unroll
        for (int n = 0; n < 4; n++)
          acc[m][n] = __builtin_amdgcn_mfma_f32_16x16x32_bf16(af[m], bfr[n], acc[m][n], 0, 0, 0);
    }
  }
  float* Sp = Spart + ((size_t)split * B_ + b) * C_ * C_;
#pragma unroll
  for (int m = 0; m < 4; m++)
#pragma unroll
    for (int n = 0; n < 4; n++) {
      int r0 = ti * 128 + wr * 64 + m * 16 + ((lane >> 4) << 2);
      int c0 = tj * 128 + wc * 64 + n * 16 + (lane & 15);
#pragma unroll
      for (int r = 0; r < 4; r++)
        Sp[(size_t)(r0 + r) * C_ + c0] = acc[m][n][r];
    }
}

// S = sum over splits of Spart.
__global__ __launch_bounds__(256) void k_sreduce(const float* __restrict__ Spart,
                                                 float* __restrict__ S) {
  size_t idx = (size_t)blockIdx.x * 256 + threadIdx.x;
  float acc = 0.f;
  for (int sp = 0; sp < SPLITK; sp++) acc += Spart[(size_t)sp * B_ * C_ * C_ + idx];
  S[idx] = acc;
}

// ps[b,o]=phi_w[o,:].s[b]; gs[b,o]=g_w[o,:].s[b]
__global__ __launch_bounds__(256) void k_psgs(const float* __restrict__ s,
                                              const float* __restrict__ phi_w,
                                              const float* __restrict__ g_w,
                                              float* __restrict__ ps,
                                              float* __restrict__ gs) {
  int b = blockIdx.x;
  __shared__ float sl[C_];
  sl[threadIdx.x] = s[b * C_ + threadIdx.x];
  __syncthreads();
  int o = threadIdx.x & 127;
  const float* w = (threadIdx.x < 128) ? phi_w : g_w;
  float acc = 0.f;
  for (int c = 0; c < C_; c++) acc += w[o * C_ + c] * sl[c];
  if (threadIdx.x < 128) ps[b * OC_ + o] = acc;
  else                   gs[b * OC_ + o] = acc;
}

// T1[b,o,:] = phi_w[o,:] @ S[b]
__global__ __launch_bounds__(256) void k_t1(const float* __restrict__ S,
                                            const float* __restrict__ phi_w,
                                            float* __restrict__ T1) {
  int b = blockIdx.x >> 7, o = blockIdx.x & 127;
  __shared__ float pw[C_];
  pw[threadIdx.x] = phi_w[o * C_ + threadIdx.x];
  __syncthreads();
  const float* Sb = S + (size_t)b * C_ * C_;
  float acc = 0.f;
  for (int c = 0; c < C_; c++) acc += pw[c] * Sb[(size_t)c * C_ + threadIdx.x];
  T1[((size_t)b * OC_ + o) * C_ + threadIdx.x] = acc;
}

// M[b,op,o] = T1[b,op,:].g_w[o,:] + rank-1 terms
__global__ __launch_bounds__(128) void k_m(const float* __restrict__ T1,
                                           const float* __restrict__ g_w,
                                           const float* __restrict__ phi_b,
                                           const float* __restrict__ g_b,
                                           const float* __restrict__ ps,
                                           const float* __restrict__ gs,
                                           float* __restrict__ M) {
  int b = blockIdx.x >> 7, op = blockIdx.x & 127;
  __shared__ float t1[C_];
  t1[threadIdx.x] = T1[((size_t)b * OC_ + op) * C_ + threadIdx.x];
  t1[threadIdx.x + 128] = T1[((size_t)b * OC_ + op) * C_ + threadIdx.x + 128];
  __syncthreads();
  int o = threadIdx.x;
  float acc = 0.f;
  for (int c = 0; c < C_; c++) acc += t1[c] * g_w[o * C_ + c];
  acc += phi_b[op] * gs[b * OC_ + o] + ps[b * OC_ + op] * g_b[o] +
         (float)L_ * phi_b[op] * g_b[o];
  M[((size_t)b * OC_ + op) * OC_ + o] = acc;
}

// U[b,c,op] = (W_w[c,:].M[b,op,:])/L ; q[b,c] = U.theta_b + W_b
__global__ __launch_bounds__(128) void k_uq(const float* __restrict__ M,
                                            const float* __restrict__ W_w,
                                            const float* __restrict__ theta_b,
                                            const float* __restrict__ W_b,
                                            float* __restrict__ U,
                                            float* __restrict__ q) {
  int b = blockIdx.x >> 8, c = blockIdx.x & 255;
  __shared__ float wr_[OC_];
  wr_[threadIdx.x] = W_w[c * OC_ + threadIdx.x];
  __syncthreads();
  int op = threadIdx.x;
  const float* Mb = M + (size_t)b * OC_ * OC_;
  float acc = 0.f;
  for (int o = 0; o < OC_; o++) acc += wr_[o] * Mb[(size_t)op * OC_ + o];
  acc *= (1.0f / (float)L_);
  U[((size_t)b * C_ + c) * OC_ + op] = acc;
  __shared__ float red[OC_];
  float tot = blockReduceSum(acc * theta_b[op], red, OC_);
  if (threadIdx.x == 0) q[b * C_ + c] = tot + W_b[c];
}

// Q[b,c,:] = U[b,c,:] @ theta_w
__global__ __launch_bounds__(256) void k_q(const float* __restrict__ U,
                                           const float* __restrict__ theta_w,
                                           float* __restrict__ Q) {
  int b = blockIdx.x >> 8, c = blockIdx.x & 255;
  __shared__ float u[OC_];
  if (threadIdx.x < OC_) u[threadIdx.x] = U[((size_t)b * C_ + c) * OC_ + threadIdx.x];
  __syncthreads();
  float acc = 0.f;
  for (int op = 0; op < OC_; op++) acc += u[op] * theta_w[(size_t)op * C_ + threadIdx.x];
  Q[((size_t)b * C_ + c) * C_ + threadIdx.x] = acc;
}

// BN partial stats from S,s
__global__ __launch_bounds__(256) void k_stats(const float* __restrict__ Q,
                                               const float* __restrict__ S,
                                               const float* __restrict__ s,
                                               const float* __restrict__ q,
                                               float* __restrict__ sum1,
                                               float* __restrict__ sum2) {
  int b = blockIdx.x >> 8, c = blockIdx.x & 255;
  __shared__ float qrow[C_];
  qrow[threadIdx.x] = Q[((size_t)b * C_ + c) * C_ + threadIdx.x];
  __syncthreads();
  const float* Sb = S + (size_t)b * C_ * C_;
  float r = 0.f;
  for (int cp = 0; cp < C_; cp++) r += qrow[cp] * Sb[(size_t)cp * C_ + threadIdx.x];
  __shared__ float red[C_];
  float e2 = blockReduceSum(r * qrow[threadIdx.x], red, C_);
  float qs = blockReduceSum(qrow[threadIdx.x] * s[b * C_ + threadIdx.x], red, C_);
  if (threadIdx.x == 0) {
    float qv = q[b * C_ + c];
    sum1[b * C_ + c] = qs + (float)L_ * qv;
    sum2[b * C_ + c] = e2 + 2.f * qv * qs + (float)L_ * qv * qv;
  }
}

// Fold BN into Qs (bf16, NO identity) and qp; residual stays fp32 in k_out.
__global__ __launch_bounds__(256) void k_build(const float* __restrict__ Q,
                                               const float* __restrict__ q,
                                               const float* __restrict__ sum1,
                                               const float* __restrict__ sum2,
                                               const float* __restrict__ gamma,
                                               const float* __restrict__ beta,
                                               u16* __restrict__ Qsb,
                                               float* __restrict__ qp) {
  int b = blockIdx.x >> 8, c = blockIdx.x & 255;
  float m = 0.f, e = 0.f;
  for (int bb = 0; bb < B_; bb++) {
    m += sum1[bb * C_ + c];
    e += sum2[bb * C_ + c];
  }
  const float inv_n = 1.f / (float)(B_ * L_);
  m *= inv_n;
  e *= inv_n;
  float var = e - m * m;
  float gsc = gamma[c] * rsqrtf(var + EPS_);
  size_t base = ((size_t)b * C_ + c) * C_;
  Qsb[base + threadIdx.x] = f2bf(gsc * Q[base + threadIdx.x]);
  if (threadIdx.x == 0) qp[b * C_ + c] = gsc * (q[b * C_ + c] - m) + beta[c];
}

// out[b] = Qs[b] @ Xb[b] + x[b] + qp[b].  grid: (L/128, C/128, B), 256 thr.
__global__ __launch_bounds__(256) void k_out(const u16* __restrict__ Qsb,
                                             const float* __restrict__ qp,
                                             const u16* __restrict__ XbT,
                                             const float* __restrict__ x,
                                             float* __restrict__ out) {
  const int b = blockIdx.z, ct = blockIdx.y, lt = blockIdx.x;
  __shared__ u16 lds[2 * 128 * 64];
  const int tid = threadIdx.x, lane = tid & 63;
  const int wid = tid >> 6, wr = wid >> 1, wc = wid & 1;
  const u16* Abase = Qsb + ((size_t)b * C_ + ct * 128) * C_;
  const u16* Bbase = XbT + ((size_t)b * L_ + lt * 128) * C_;
  f32x4 acc[4][4] = {};
  for (int k0 = 0; k0 < C_; k0 += 64) {
    __syncthreads();
#pragma unroll
    for (int ch = 0; ch < 4; ch++) {
      int d = ch * 4096 + tid * 16;
      int row = d >> 7;
      int kb = (d & 127) ^ ((row & 7) << 4);
      gload_lds16(Abase + (size_t)row * C_ + k0 + (kb >> 1), (char*)lds + d);
      gload_lds16(Bbase + (size_t)row * C_ + k0 + (kb >> 1), (char*)lds + 16384 + d);
    }
    asm volatile("s_waitcnt vmcnt(0)" ::: "memory");
    __syncthreads();
#pragma unroll
    for (int ks = 0; ks < 2; ks++) {
      bf16x8 af[4], bfr[4];
#pragma unroll
      for (int m = 0; m < 4; m++) {
        int row = wr * 64 + m * 16 + (lane & 15);
        int kb = ((ks << 6) + ((lane >> 4) << 4)) ^ ((row & 7) << 4);
        af[m] = *(const bf16x8*)((const char*)lds + row * 128 + kb);
      }
#pragma unroll
      for (int n = 0; n < 4; n++) {
        int row = wc * 64 + n * 16 + (lane & 15);
        int kb = ((ks << 6) + ((lane >> 4) << 4)) ^ ((row & 7) << 4);
        bfr[n] = *(const bf16x8*)((const char*)lds + 16384 + row * 128 + kb);
      }
#pragma unroll
      for (int m = 0; m < 4; m++)
#pragma unroll
        for (int n = 0; n < 4; n++)
          acc[m][n] = __builtin_amdgcn_mfma_f32_16x16x32_bf16(af[m], bfr[n], acc[m][n], 0, 0, 0);
    }
  }
#pragma unroll
  for (int m = 0; m < 4; m++)
#pragma unroll
    for (int n = 0; n < 4; n++) {
      int c = ct * 128 + wr * 64 + m * 16 + ((lane >> 4) << 2);
      int l = lt * 128 + wc * 64 + n * 16 + (lane & 15);
#pragma unroll
      for (int r = 0; r < 4; r++) {
        size_t gi = ((size_t)b * C_ + c + r) * L_ + l;
        out[gi] = acc[m][n][r] + x[gi] + qp[b * C_ + c + r];
      }
    }
}

extern "C" void kernel_launch(void* const* d_in, const int* in_sizes, int n_in,
                              void* d_out, int out_size, void* d_ws, size_t ws_size,
                              hipStream_t stream) {
  const float* x       = (const float*)d_in[0];
  const float* g_w     = (const float*)d_in[1];
  const float* g_b     = (const float*)d_in[2];
  const float* theta_w = (const float*)d_in[3];
  const float* theta_b = (const float*)d_in[4];
  const float* phi_w   = (const float*)d_in[5];
  const float* phi_b   = (const float*)d_in[6];
  const float* W_w     = (const float*)d_in[7];
  const float* W_b     = (const float*)d_in[8];
  const float* gamma   = (const float*)d_in[9];
  const float* beta    = (const float*)d_in[10];
  float* out = (float*)d_out;

  float* ws = (float*)d_ws;
  size_t off = 0;
  float* Spart = ws + off; off += (size_t)SPLITK * B_ * C_ * C_;  // 16MB
  float* S     = ws + off; off += (size_t)B_ * C_ * C_;
  float* s_    = ws + off; off += B_ * C_;
  float* ps    = ws + off; off += B_ * OC_;
  float* gs    = ws + off; off += B_ * OC_;
  float* T1    = ws + off; off += (size_t)B_ * OC_ * C_;
  float* M     = ws + off; off += (size_t)B_ * OC_ * OC_;
  float* U     = ws + off; off += (size_t)B_ * C_ * OC_;
  float* qv    = ws + off; off += B_ * C_;
  float* Q     = ws + off; off += (size_t)B_ * C_ * C_;
  float* sum1  = ws + off; off += B_ * C_;
  float* sum2  = ws + off; off += B_ * C_;
  float* qp    = ws + off; off += B_ * C_;
  u16* Qsb = (u16*)(ws + off); off += (size_t)B_ * C_ * C_ / 2;
  u16* Xb  = (u16*)(ws + off); off += (size_t)B_ * C_ * L_ / 2;
  u16* XbT = (u16*)(ws + off); off += (size_t)B_ * C_ * L_ / 2;

  k_cvt<<<dim3(L_ / 64, C_ / 64, B_), 256, 0, stream>>>(x, Xb, XbT);
  k_rowsum<<<B_ * C_, 256, 0, stream>>>(x, s_);
  k_xxt<<<dim3(4, SPLITK, B_), 256, 0, stream>>>(Xb, Spart);
  k_sreduce<<<(B_ * C_ * C_) / 256, 256, 0, stream>>>(Spart, S);
  k_psgs<<<B_, 256, 0, stream>>>(s_, phi_w, g_w, ps, gs);
  k_t1<<<B_ * OC_, 256, 0, stream>>>(S, phi_w, T1);
  k_m<<<B_ * OC_, 128, 0, stream>>>(T1, g_w, phi_b, g_b, ps, gs, M);
  k_uq<<<B_ * C_, 128, 0, stream>>>(M, W_w, theta_b, W_b, U, qv);
  k_q<<<B_ * C_, 256, 0, stream>>>(U, theta_w, Q);
  k_stats<<<B_ * C_, 256, 0, stream>>>(Q, S, s_, qv, sum1, sum2);
  k_build<<<B_ * C_, 256, 0, stream>>>(Q, qv, sum1, sum2, gamma, beta, Qsb, qp);
  k_out<<<dim3(L_ / 128, C_ / 128, B_), 256, 0, stream>>>(Qsb, qp, XbT, x, out);
}

// Round 3
// 143.127 us; speedup vs baseline: 1.9141x; 1.1011x over previous
//
#include <hip/hip_runtime.h>
#include <hip/hip_bf16.h>

#define B_ 8
#define C_ 256
#define OC_ 128
#define L_ 4096
#define EPS_ 1e-5f
#define SPLITK 8

typedef unsigned short u16;
typedef __attribute__((ext_vector_type(4))) unsigned short u16x4;
typedef __attribute__((ext_vector_type(8))) unsigned short u16x8;
typedef __attribute__((ext_vector_type(4))) float f32x4;
typedef __attribute__((ext_vector_type(8))) short bf16x8;

__device__ inline u16 f2bf(float f) {
  union { __hip_bfloat16 h; u16 u; } v;
  v.h = __float2bfloat16(f);
  return v.u;
}
__device__ inline float bf2f(u16 u) {
  union { float f; unsigned u; } v;
  v.u = ((unsigned)u) << 16;
  return v.f;
}

__device__ inline void gload_lds16(const void* g, void* lds) {
  __builtin_amdgcn_global_load_lds(
      (const __attribute__((address_space(1))) unsigned int*)g,
      (__attribute__((address_space(3))) unsigned int*)lds, 16, 0, 0);
}

__device__ inline float blockReduceSum(float v, float* red, int nthreads) {
  int tid = threadIdx.x;
  red[tid] = v;
  __syncthreads();
  for (int s = nthreads >> 1; s > 0; s >>= 1) {
    if (tid < s) red[tid] += red[tid + s];
    __syncthreads();
  }
  float r = red[0];
  __syncthreads();
  return r;
}

// Convert x -> bf16 in both layouts: Xb[b][c][l], XbT[b][l][c]
__global__ __launch_bounds__(256) void k_cvt(const float* __restrict__ x,
                                             u16* __restrict__ Xb,
                                             u16* __restrict__ XbT) {
  __shared__ u16 T[64][72];
  const int b = blockIdx.z, c0 = blockIdx.y * 64, l0 = blockIdx.x * 64;
  const int tid = threadIdx.x;
#pragma unroll
  for (int it = 0; it < 4; ++it) {
    int idx = it * 256 + tid;
    int row = idx >> 4;          // c within tile
    int col = (idx & 15) << 2;   // l within tile
    size_t gi = ((size_t)(b * C_ + c0 + row)) * L_ + l0 + col;
    float4 v = *(const float4*)(x + gi);
    u16 u0 = f2bf(v.x), u1 = f2bf(v.y), u2 = f2bf(v.z), u3 = f2bf(v.w);
    u16x4 u = {u0, u1, u2, u3};
    *(u16x4*)(Xb + gi) = u;
    T[row][col] = u0; T[row][col + 1] = u1; T[row][col + 2] = u2; T[row][col + 3] = u3;
  }
  __syncthreads();
#pragma unroll
  for (int it = 0; it < 4; ++it) {
    int idx = it * 256 + tid;
    int lrow = idx >> 4;
    int ccol = (idx & 15) << 2;
    u16x4 u = {T[ccol][lrow], T[ccol + 1][lrow], T[ccol + 2][lrow], T[ccol + 3][lrow]};
    *(u16x4*)(XbT + ((size_t)b * L_ + l0 + lrow) * C_ + c0 + ccol) = u;
  }
}

// s[b,c] = sum_l Xb[b,c,l]  (bf16 input: 8x less traffic than fp32 x)
__global__ __launch_bounds__(256) void k_rowsum(const u16* __restrict__ Xb,
                                                float* __restrict__ s) {
  int row = blockIdx.x;  // b*C + c
  const u16x8* xr = (const u16x8*)(Xb + (size_t)row * L_);
  float acc = 0.f;
  for (int i = threadIdx.x; i < L_ / 8; i += 256) {
    u16x8 v = xr[i];
#pragma unroll
    for (int j = 0; j < 8; j++) acc += bf2f(v[j]);
  }
  __shared__ float red[256];
  float tot = blockReduceSum(acc, red, 256);
  if (threadIdx.x == 0) s[row] = tot;
}

// S[b] = Xb Xb^T via MFMA bf16, split-K. grid: (4, SPLITK, B), 256 thr.
__global__ __launch_bounds__(256) void k_xxt(const u16* __restrict__ Xb,
                                             float* __restrict__ Spart) {
  const int b = blockIdx.z, split = blockIdx.y;
  const int ti = blockIdx.x >> 1, tj = blockIdx.x & 1;
  __shared__ u16 lds[2 * 128 * 64];
  const int tid = threadIdx.x, lane = tid & 63;
  const int wid = tid >> 6, wr = wid >> 1, wc = wid & 1;
  const u16* Arows = Xb + ((size_t)b * C_ + ti * 128) * L_;
  const u16* Brows = Xb + ((size_t)b * C_ + tj * 128) * L_;
  const int k0 = split * (L_ / SPLITK);
  f32x4 acc[4][4] = {};
  for (int kt = 0; kt < L_ / SPLITK; kt += 64) {
    __syncthreads();
#pragma unroll
    for (int ch = 0; ch < 4; ch++) {
      int d = ch * 4096 + tid * 16;
      int row = d >> 7;
      int kb = (d & 127) ^ ((row & 7) << 4);
      gload_lds16(Arows + (size_t)row * L_ + k0 + kt + (kb >> 1), (char*)lds + d);
      gload_lds16(Brows + (size_t)row * L_ + k0 + kt + (kb >> 1), (char*)lds + 16384 + d);
    }
    asm volatile("s_waitcnt vmcnt(0)" ::: "memory");
    __syncthreads();
#pragma unroll
    for (int ks = 0; ks < 2; ks++) {
      bf16x8 af[4], bfr[4];
#pragma unroll
      for (int m = 0; m < 4; m++) {
        int row = wr * 64 + m * 16 + (lane & 15);
        int kb = ((ks << 6) + ((lane >> 4) << 4)) ^ ((row & 7) << 4);
        af[m] = *(const bf16x8*)((const char*)lds + row * 128 + kb);
      }
#pragma unroll
      for (int n = 0; n < 4; n++) {
        int row = wc * 64 + n * 16 + (lane & 15);
        int kb = ((ks << 6) + ((lane >> 4) << 4)) ^ ((row & 7) << 4);
        bfr[n] = *(const bf16x8*)((const char*)lds + 16384 + row * 128 + kb);
      }
#pragma unroll
      for (int m = 0; m < 4; m++)
#pragma unroll
        for (int n = 0; n < 4; n++)
          acc[m][n] = __builtin_amdgcn_mfma_f32_16x16x32_bf16(af[m], bfr[n], acc[m][n], 0, 0, 0);
    }
  }
  float* Sp = Spart + ((size_t)split * B_ + b) * C_ * C_;
#pragma unroll
  for (int m = 0; m < 4; m++)
#pragma unroll
    for (int n = 0; n < 4; n++) {
      int r0 = ti * 128 + wr * 64 + m * 16 + ((lane >> 4) << 2);
      int c0 = tj * 128 + wc * 64 + n * 16 + (lane & 15);
#pragma unroll
      for (int r = 0; r < 4; r++)
        Sp[(size_t)(r0 + r) * C_ + c0] = acc[m][n][r];
    }
}

__global__ __launch_bounds__(256) void k_sreduce(const float* __restrict__ Spart,
                                                 float* __restrict__ S) {
  size_t idx = (size_t)blockIdx.x * 256 + threadIdx.x;
  float acc = 0.f;
  for (int sp = 0; sp < SPLITK; sp++) acc += Spart[(size_t)sp * B_ * C_ * C_ + idx];
  S[idx] = acc;
}

// Fused psgs+t1+m: M[b,op,o] = sum_c (T1row[c]+phi_b*s[c])*g_w[o,c] + (ps+L*phi_b)*g_b[o]
// grid: B*OC blocks, 256 thr.
__global__ __launch_bounds__(256) void k_mid1(const float* __restrict__ S,
                                              const float* __restrict__ s,
                                              const float* __restrict__ phi_w,
                                              const float* __restrict__ phi_b,
                                              const float* __restrict__ g_w,
                                              const float* __restrict__ g_b,
                                              float* __restrict__ M) {
  const int b = blockIdx.x >> 7, op = blockIdx.x & 127;
  const int tid = threadIdx.x;
  __shared__ float sl[C_], pw[C_], t2[C_], red[256];
  sl[tid] = s[b * C_ + tid];
  pw[tid] = phi_w[op * C_ + tid];
  __syncthreads();
  float ps_op = blockReduceSum(pw[tid] * sl[tid], red, 256);
  float phb = phi_b[op];
  const float* Sb = S + (size_t)b * C_ * C_;
  float t1 = 0.f;
  for (int cp = 0; cp < C_; cp++) t1 += pw[cp] * Sb[(size_t)cp * C_ + tid];
  t2[tid] = t1 + phb * sl[tid];
  __syncthreads();
  if (tid < OC_) {
    int o = tid;
    const float* gr = g_w + o * C_;
    float acc = 0.f;
    for (int c = 0; c < C_; c++) acc += t2[c] * gr[c];
    M[((size_t)b * OC_ + op) * OC_ + o] = acc + (ps_op + (float)L_ * phb) * g_b[o];
  }
}

// Fused uq+q: U row -> q scalar -> Q row.  grid: B*C blocks, 128 thr.
__global__ __launch_bounds__(128) void k_mid2(const float* __restrict__ M,
                                              const float* __restrict__ W_w,
                                              const float* __restrict__ theta_w,
                                              const float* __restrict__ theta_b,
                                              const float* __restrict__ W_b,
                                              float* __restrict__ Q,
                                              float* __restrict__ q) {
  const int b = blockIdx.x >> 8, c = blockIdx.x & 255;
  const int tid = threadIdx.x;
  __shared__ float wr_[OC_], U_s[OC_], red[OC_];
  wr_[tid] = W_w[c * OC_ + tid];
  __syncthreads();
  const float* Mb = M + (size_t)b * OC_ * OC_;
  float acc = 0.f;
  for (int o = 0; o < OC_; o++) acc += wr_[o] * Mb[(size_t)tid * OC_ + o];
  acc *= (1.0f / (float)L_);
  U_s[tid] = acc;
  float tot = blockReduceSum(acc * theta_b[tid], red, OC_);
  if (tid == 0) q[b * C_ + c] = tot + W_b[c];
#pragma unroll
  for (int h = 0; h < 2; h++) {
    int ch = tid + h * OC_;
    float a2 = 0.f;
    for (int op = 0; op < OC_; op++) a2 += U_s[op] * theta_w[(size_t)op * C_ + ch];
    Q[((size_t)b * C_ + c) * C_ + ch] = a2;
  }
}

// BN partial stats from S,s
__global__ __launch_bounds__(256) void k_stats(const float* __restrict__ Q,
                                               const float* __restrict__ S,
                                               const float* __restrict__ s,
                                               const float* __restrict__ q,
                                               float* __restrict__ sum1,
                                               float* __restrict__ sum2) {
  int b = blockIdx.x >> 8, c = blockIdx.x & 255;
  __shared__ float qrow[C_];
  qrow[threadIdx.x] = Q[((size_t)b * C_ + c) * C_ + threadIdx.x];
  __syncthreads();
  const float* Sb = S + (size_t)b * C_ * C_;
  float r = 0.f;
  for (int cp = 0; cp < C_; cp++) r += qrow[cp] * Sb[(size_t)cp * C_ + threadIdx.x];
  __shared__ float red[C_];
  float e2 = blockReduceSum(r * qrow[threadIdx.x], red, C_);
  float qs = blockReduceSum(qrow[threadIdx.x] * s[b * C_ + threadIdx.x], red, C_);
  if (threadIdx.x == 0) {
    float qv = q[b * C_ + c];
    sum1[b * C_ + c] = qs + (float)L_ * qv;
    sum2[b * C_ + c] = e2 + 2.f * qv * qs + (float)L_ * qv * qv;
  }
}

// Fold BN into Qs (bf16, NO identity) and qp.
__global__ __launch_bounds__(256) void k_build(const float* __restrict__ Q,
                                               const float* __restrict__ q,
                                               const float* __restrict__ sum1,
                                               const float* __restrict__ sum2,
                                               const float* __restrict__ gamma,
                                               const float* __restrict__ beta,
                                               u16* __restrict__ Qsb,
                                               float* __restrict__ qp) {
  int b = blockIdx.x >> 8, c = blockIdx.x & 255;
  float m = 0.f, e = 0.f;
  for (int bb = 0; bb < B_; bb++) {
    m += sum1[bb * C_ + c];
    e += sum2[bb * C_ + c];
  }
  const float inv_n = 1.f / (float)(B_ * L_);
  m *= inv_n;
  e *= inv_n;
  float var = e - m * m;
  float gsc = gamma[c] * rsqrtf(var + EPS_);
  size_t base = ((size_t)b * C_ + c) * C_;
  Qsb[base + threadIdx.x] = f2bf(gsc * Q[base + threadIdx.x]);
  if (threadIdx.x == 0) qp[b * C_ + c] = gsc * (q[b * C_ + c] - m) + beta[c];
}

// out[b] = Qs[b] @ Xb[b] + bf16(x[b]) + qp[b].  grid: (L/128, C/128, B), 256 thr.
__global__ __launch_bounds__(256) void k_out(const u16* __restrict__ Qsb,
                                             const float* __restrict__ qp,
                                             const u16* __restrict__ XbT,
                                             const u16* __restrict__ Xb,
                                             float* __restrict__ out) {
  const int b = blockIdx.z, ct = blockIdx.y, lt = blockIdx.x;
  __shared__ u16 lds[2 * 128 * 64];
  const int tid = threadIdx.x, lane = tid & 63;
  const int wid = tid >> 6, wr = wid >> 1, wc = wid & 1;
  const u16* Abase = Qsb + ((size_t)b * C_ + ct * 128) * C_;
  const u16* Bbase = XbT + ((size_t)b * L_ + lt * 128) * C_;
  f32x4 acc[4][4] = {};
  for (int k0 = 0; k0 < C_; k0 += 64) {
    __syncthreads();
#pragma unroll
    for (int ch = 0; ch < 4; ch++) {
      int d = ch * 4096 + tid * 16;
      int row = d >> 7;
      int kb = (d & 127) ^ ((row & 7) << 4);
      gload_lds16(Abase + (size_t)row * C_ + k0 + (kb >> 1), (char*)lds + d);
      gload_lds16(Bbase + (size_t)row * C_ + k0 + (kb >> 1), (char*)lds + 16384 + d);
    }
    asm volatile("s_waitcnt vmcnt(0)" ::: "memory");
    __syncthreads();
#pragma unroll
    for (int ks = 0; ks < 2; ks++) {
      bf16x8 af[4], bfr[4];
#pragma unroll
      for (int m = 0; m < 4; m++) {
        int row = wr * 64 + m * 16 + (lane & 15);
        int kb = ((ks << 6) + ((lane >> 4) << 4)) ^ ((row & 7) << 4);
        af[m] = *(const bf16x8*)((const char*)lds + row * 128 + kb);
      }
#pragma unroll
      for (int n = 0; n < 4; n++) {
        int row = wc * 64 + n * 16 + (lane & 15);
        int kb = ((ks << 6) + ((lane >> 4) << 4)) ^ ((row & 7) << 4);
        bfr[n] = *(const bf16x8*)((const char*)lds + 16384 + row * 128 + kb);
      }
#pragma unroll
      for (int m = 0; m < 4; m++)
#pragma unroll
        for (int n = 0; n < 4; n++)
          acc[m][n] = __builtin_amdgcn_mfma_f32_16x16x32_bf16(af[m], bfr[n], acc[m][n], 0, 0, 0);
    }
  }
#pragma unroll
  for (int m = 0; m < 4; m++)
#pragma unroll
    for (int n = 0; n < 4; n++) {
      int c = ct * 128 + wr * 64 + m * 16 + ((lane >> 4) << 2);
      int l = lt * 128 + wc * 64 + n * 16 + (lane & 15);
#pragma unroll
      for (int r = 0; r < 4; r++) {
        size_t gi = ((size_t)b * C_ + c + r) * L_ + l;
        out[gi] = acc[m][n][r] + bf2f(Xb[gi]) + qp[b * C_ + c + r];
      }
    }
}

extern "C" void kernel_launch(void* const* d_in, const int* in_sizes, int n_in,
                              void* d_out, int out_size, void* d_ws, size_t ws_size,
                              hipStream_t stream) {
  const float* x       = (const float*)d_in[0];
  const float* g_w     = (const float*)d_in[1];
  const float* g_b     = (const float*)d_in[2];
  const float* theta_w = (const float*)d_in[3];
  const float* theta_b = (const float*)d_in[4];
  const float* phi_w   = (const float*)d_in[5];
  const float* phi_b   = (const float*)d_in[6];
  const float* W_w     = (const float*)d_in[7];
  const float* W_b     = (const float*)d_in[8];
  const float* gamma   = (const float*)d_in[9];
  const float* beta    = (const float*)d_in[10];
  float* out = (float*)d_out;

  float* ws = (float*)d_ws;
  size_t off = 0;
  float* Spart = ws + off; off += (size_t)SPLITK * B_ * C_ * C_;
  float* S     = ws + off; off += (size_t)B_ * C_ * C_;
  float* s_    = ws + off; off += B_ * C_;
  float* M     = ws + off; off += (size_t)B_ * OC_ * OC_;
  float* qv    = ws + off; off += B_ * C_;
  float* Q     = ws + off; off += (size_t)B_ * C_ * C_;
  float* sum1  = ws + off; off += B_ * C_;
  float* sum2  = ws + off; off += B_ * C_;
  float* qp    = ws + off; off += B_ * C_;
  u16* Qsb = (u16*)(ws + off); off += (size_t)B_ * C_ * C_ / 2;
  u16* Xb  = (u16*)(ws + off); off += (size_t)B_ * C_ * L_ / 2;
  u16* XbT = (u16*)(ws + off); off += (size_t)B_ * C_ * L_ / 2;

  k_cvt<<<dim3(L_ / 64, C_ / 64, B_), 256, 0, stream>>>(x, Xb, XbT);
  k_rowsum<<<B_ * C_, 256, 0, stream>>>(Xb, s_);
  k_xxt<<<dim3(4, SPLITK, B_), 256, 0, stream>>>(Xb, Spart);
  k_sreduce<<<(B_ * C_ * C_) / 256, 256, 0, stream>>>(Spart, S);
  k_mid1<<<B_ * OC_, 256, 0, stream>>>(S, s_, phi_w, phi_b, g_w, g_b, M);
  k_mid2<<<B_ * C_, 128, 0, stream>>>(M, W_w, theta_w, theta_b, W_b, Q, qv);
  k_stats<<<B_ * C_, 256, 0, stream>>>(Q, S, s_, qv, sum1, sum2);
  k_build<<<B_ * C_, 256, 0, stream>>>(Q, qv, sum1, sum2, gamma, beta, Qsb, qp);
  k_out<<<dim3(L_ / 128, C_ / 128, B_), 256, 0, stream>>>(Qsb, qp, XbT, Xb, out);
}

// Round 4
// 118.378 us; speedup vs baseline: 2.3143x; 1.2091x over previous
//
#include <hip/hip_runtime.h>
#include <hip/hip_bf16.h>

#define B_ 8
#define C_ 256
#define OC_ 128
#define L_ 4096
#define EPS_ 1e-5f
#define SPLITK 8

typedef unsigned short u16;
typedef __attribute__((ext_vector_type(4))) unsigned short u16x4;
typedef __attribute__((ext_vector_type(4))) float f32x4;
typedef __attribute__((ext_vector_type(8))) short bf16x8;

__device__ inline u16 f2bf(float f) {
  union { __hip_bfloat16 h; u16 u; } v;
  v.h = __float2bfloat16(f);
  return v.u;
}
__device__ inline float bf2f(u16 u) {
  union { float f; unsigned u; } v;
  v.u = ((unsigned)u) << 16;
  return v.f;
}

__device__ inline void gload_lds16(const void* g, void* lds) {
  __builtin_amdgcn_global_load_lds(
      (const __attribute__((address_space(1))) unsigned int*)g,
      (__attribute__((address_space(3))) unsigned int*)lds, 16, 0, 0);
}

__device__ inline float blockReduceSum(float v, float* red, int nthreads) {
  int tid = threadIdx.x;
  red[tid] = v;
  __syncthreads();
  for (int s = nthreads >> 1; s > 0; s >>= 1) {
    if (tid < s) red[tid] += red[tid + s];
    __syncthreads();
  }
  float r = red[0];
  __syncthreads();
  return r;
}

// x -> Xb[b][c][l], XbT[b][l][c] (bf16), + partial row sums spartial[b*C+c][ltile]
__global__ __launch_bounds__(256) void k_cvt(const float* __restrict__ x,
                                             u16* __restrict__ Xb,
                                             u16* __restrict__ XbT,
                                             float* __restrict__ spartial) {
  __shared__ u16 T[64][73];
  __shared__ float P[64][17];
  const int b = blockIdx.z, c0 = blockIdx.y * 64, l0 = blockIdx.x * 64;
  const int tid = threadIdx.x;
#pragma unroll
  for (int it = 0; it < 4; ++it) {
    int idx = it * 256 + tid;
    int row = idx >> 4;          // c within tile
    int col = (idx & 15) << 2;   // l within tile
    size_t gi = ((size_t)(b * C_ + c0 + row)) * L_ + l0 + col;
    float4 v = *(const float4*)(x + gi);
    u16 u0 = f2bf(v.x), u1 = f2bf(v.y), u2 = f2bf(v.z), u3 = f2bf(v.w);
    u16x4 u = {u0, u1, u2, u3};
    *(u16x4*)(Xb + gi) = u;
    T[row][col] = u0; T[row][col + 1] = u1; T[row][col + 2] = u2; T[row][col + 3] = u3;
    P[row][idx & 15] = v.x + v.y + v.z + v.w;
  }
  __syncthreads();
  if (tid < 64) {
    float acc = 0.f;
#pragma unroll
    for (int j = 0; j < 16; j++) acc += P[tid][j];
    spartial[(size_t)(b * C_ + c0 + tid) * 64 + blockIdx.x] = acc;
  }
#pragma unroll
  for (int it = 0; it < 4; ++it) {
    int idx = it * 256 + tid;
    int lrow = idx >> 4;
    int ccol = (idx & 15) << 2;
    u16x4 u = {T[ccol][lrow], T[ccol + 1][lrow], T[ccol + 2][lrow], T[ccol + 3][lrow]};
    *(u16x4*)(XbT + ((size_t)b * L_ + l0 + lrow) * C_ + c0 + ccol) = u;
  }
}

// S[b] = Xb Xb^T via MFMA bf16, split-K. grid: (4, SPLITK, B), 256 thr.
__global__ __launch_bounds__(256) void k_xxt(const u16* __restrict__ Xb,
                                             float* __restrict__ Spart) {
  const int b = blockIdx.z, split = blockIdx.y;
  const int ti = blockIdx.x >> 1, tj = blockIdx.x & 1;
  __shared__ u16 lds[2 * 128 * 64];
  const int tid = threadIdx.x, lane = tid & 63;
  const int wid = tid >> 6, wr = wid >> 1, wc = wid & 1;
  const u16* Arows = Xb + ((size_t)b * C_ + ti * 128) * L_;
  const u16* Brows = Xb + ((size_t)b * C_ + tj * 128) * L_;
  const int k0 = split * (L_ / SPLITK);
  f32x4 acc[4][4] = {};
  for (int kt = 0; kt < L_ / SPLITK; kt += 64) {
    __syncthreads();
#pragma unroll
    for (int ch = 0; ch < 4; ch++) {
      int d = ch * 4096 + tid * 16;
      int row = d >> 7;
      int kb = (d & 127) ^ ((row & 7) << 4);
      gload_lds16(Arows + (size_t)row * L_ + k0 + kt + (kb >> 1), (char*)lds + d);
      gload_lds16(Brows + (size_t)row * L_ + k0 + kt + (kb >> 1), (char*)lds + 16384 + d);
    }
    asm volatile("s_waitcnt vmcnt(0)" ::: "memory");
    __syncthreads();
#pragma unroll
    for (int ks = 0; ks < 2; ks++) {
      bf16x8 af[4], bfr[4];
#pragma unroll
      for (int m = 0; m < 4; m++) {
        int row = wr * 64 + m * 16 + (lane & 15);
        int kb = ((ks << 6) + ((lane >> 4) << 4)) ^ ((row & 7) << 4);
        af[m] = *(const bf16x8*)((const char*)lds + row * 128 + kb);
      }
#pragma unroll
      for (int n = 0; n < 4; n++) {
        int row = wc * 64 + n * 16 + (lane & 15);
        int kb = ((ks << 6) + ((lane >> 4) << 4)) ^ ((row & 7) << 4);
        bfr[n] = *(const bf16x8*)((const char*)lds + 16384 + row * 128 + kb);
      }
#pragma unroll
      for (int m = 0; m < 4; m++)
#pragma unroll
        for (int n = 0; n < 4; n++)
          acc[m][n] = __builtin_amdgcn_mfma_f32_16x16x32_bf16(af[m], bfr[n], acc[m][n], 0, 0, 0);
    }
  }
  float* Sp = Spart + ((size_t)split * B_ + b) * C_ * C_;
#pragma unroll
  for (int m = 0; m < 4; m++)
#pragma unroll
    for (int n = 0; n < 4; n++) {
      int r0 = ti * 128 + wr * 64 + m * 16 + ((lane >> 4) << 2);
      int c0 = tj * 128 + wc * 64 + n * 16 + (lane & 15);
#pragma unroll
      for (int r = 0; r < 4; r++)
        Sp[(size_t)(r0 + r) * C_ + c0] = acc[m][n][r];
    }
}

// blocks <2048: S = sum Spart; 2048-2055: s = sum spartial; 2056-2071: gwT = g_w^T
__global__ __launch_bounds__(256) void k_sreduce(const float* __restrict__ Spart,
                                                 const float* __restrict__ spartial,
                                                 const float* __restrict__ g_w,
                                                 float* __restrict__ S,
                                                 float* __restrict__ s,
                                                 float* __restrict__ gwT) {
  const int bid = blockIdx.x, tid = threadIdx.x;
  if (bid < (B_ * C_ * C_) / 256) {
    size_t idx = (size_t)bid * 256 + tid;
    float acc = 0.f;
    for (int sp = 0; sp < SPLITK; sp++) acc += Spart[(size_t)sp * B_ * C_ * C_ + idx];
    S[idx] = acc;
  } else if (bid < (B_ * C_ * C_) / 256 + (B_ * C_) / 256) {
    int idx2 = (bid - (B_ * C_ * C_) / 256) * 256 + tid;  // b*C + c
    const float4* sp = (const float4*)(spartial + (size_t)idx2 * 64);
    float acc = 0.f;
#pragma unroll
    for (int i = 0; i < 16; i++) { float4 v = sp[i]; acc += v.x + v.y + v.z + v.w; }
    s[idx2] = acc;
  } else {
    int t = bid - ((B_ * C_ * C_) / 256 + (B_ * C_) / 256);  // 0..15
    int o = t * 8 + (tid & 7);
    int cbase = (tid >> 3) * 8;
#pragma unroll
    for (int k = 0; k < 8; k++) {
      int c = cbase + k;
      gwT[c * OC_ + o] = g_w[o * C_ + c];
    }
  }
}

// MT[b][o][op] = sum_c (t1[c]+phi_b*s[c])*gwT[c][o] + (ps+L*phi_b)*g_b[o]
// grid: B*OC blocks, 256 thr.
__global__ __launch_bounds__(256) void k_mid1(const float* __restrict__ S,
                                              const float* __restrict__ s,
                                              const float* __restrict__ phi_w,
                                              const float* __restrict__ phi_b,
                                              const float* __restrict__ gwT,
                                              const float* __restrict__ g_b,
                                              float* __restrict__ MT) {
  const int b = blockIdx.x >> 7, op = blockIdx.x & 127;
  const int tid = threadIdx.x;
  __shared__ float sl[C_], pw[C_], t2[C_], red[256];
  sl[tid] = s[b * C_ + tid];
  pw[tid] = phi_w[op * C_ + tid];
  __syncthreads();
  float ps_op = blockReduceSum(pw[tid] * sl[tid], red, 256);
  float phb = phi_b[op];
  const float* Sb = S + (size_t)b * C_ * C_;
  float t1 = 0.f;
  for (int cp = 0; cp < C_; cp++) t1 += pw[cp] * Sb[(size_t)cp * C_ + tid];
  t2[tid] = t1 + phb * sl[tid];
  __syncthreads();
  const int o = tid & 127, half = tid >> 7;
  float part = 0.f;
  for (int cc = 0; cc < 128; cc++) {
    int cidx = half * 128 + cc;
    part += t2[cidx] * gwT[cidx * OC_ + o];
  }
  red[tid] = part;
  __syncthreads();
  if (tid < OC_) {
    float val = red[tid] + red[tid + 128] + (ps_op + (float)L_ * phb) * g_b[tid];
    MT[((size_t)b * OC_ + tid) * OC_ + op] = val;
  }
}

// Fused uq+q+stats: U row -> q, Q row, BN partial sums. grid: B*C, 128 thr.
__global__ __launch_bounds__(128) void k_mid2stats(const float* __restrict__ MT,
                                                   const float* __restrict__ W_w,
                                                   const float* __restrict__ theta_w,
                                                   const float* __restrict__ theta_b,
                                                   const float* __restrict__ W_b,
                                                   const float* __restrict__ S,
                                                   const float* __restrict__ s,
                                                   float* __restrict__ Q,
                                                   float* __restrict__ qv,
                                                   float* __restrict__ sum1,
                                                   float* __restrict__ sum2) {
  const int b = blockIdx.x >> 8, c = blockIdx.x & 255;
  const int tid = threadIdx.x;
  __shared__ float wr_[OC_], U_s[OC_], red[OC_], qrow[C_];
  wr_[tid] = W_w[c * OC_ + tid];
  __syncthreads();
  const float* MTb = MT + (size_t)b * OC_ * OC_;
  float acc = 0.f;
  for (int o = 0; o < OC_; o++) acc += wr_[o] * MTb[(size_t)o * OC_ + tid];
  acc *= (1.0f / (float)L_);
  U_s[tid] = acc;
  float tot = blockReduceSum(acc * theta_b[tid], red, OC_);
  float q_val = tot + W_b[c];
  if (tid == 0) qv[b * C_ + c] = q_val;
  float a2[2];
#pragma unroll
  for (int h = 0; h < 2; h++) {
    int ch = tid + h * OC_;
    float a = 0.f;
    for (int op = 0; op < OC_; op++) a += U_s[op] * theta_w[(size_t)op * C_ + ch];
    a2[h] = a;
    qrow[ch] = a;
    Q[((size_t)b * C_ + c) * C_ + ch] = a;
  }
  __syncthreads();
  const float* Sb = S + (size_t)b * C_ * C_;
  float rq = 0.f, qssum = 0.f;
#pragma unroll
  for (int h = 0; h < 2; h++) {
    int ch = tid + h * OC_;
    float r = 0.f;
    for (int cp = 0; cp < C_; cp++) r += qrow[cp] * Sb[(size_t)cp * C_ + ch];
    rq += r * a2[h];
    qssum += a2[h] * s[b * C_ + ch];
  }
  float e2 = blockReduceSum(rq, red, OC_);
  float qs = blockReduceSum(qssum, red, OC_);
  if (tid == 0) {
    sum1[b * C_ + c] = qs + (float)L_ * q_val;
    sum2[b * C_ + c] = e2 + 2.f * q_val * qs + (float)L_ * q_val * q_val;
  }
}

// out[b] = (gsc*Q)[b] @ Xb[b] + bf16(x[b]) + qp.  grid: (L/128, C/128, B), 256 thr.
__global__ __launch_bounds__(256) void k_out(const float* __restrict__ Q,
                                             const float* __restrict__ qv,
                                             const float* __restrict__ sum1,
                                             const float* __restrict__ sum2,
                                             const float* __restrict__ gamma,
                                             const float* __restrict__ beta,
                                             const u16* __restrict__ XbT,
                                             const u16* __restrict__ Xb,
                                             float* __restrict__ out) {
  const int b = blockIdx.z, ct = blockIdx.y, lt = blockIdx.x;
  __shared__ u16 lds[128 * 64];
  __shared__ float gsc_s[128], qp_s[128];
  const int tid = threadIdx.x, lane = tid & 63;
  const int wid = tid >> 6, wr = wid >> 1, wc = wid & 1;
  if (tid < 128) {
    int c = ct * 128 + tid;
    float m = 0.f, e = 0.f;
#pragma unroll
    for (int bb = 0; bb < B_; bb++) {
      m += sum1[bb * C_ + c];
      e += sum2[bb * C_ + c];
    }
    const float inv_n = 1.f / (float)(B_ * L_);
    m *= inv_n;
    e *= inv_n;
    float var = e - m * m;
    float g = gamma[c] * rsqrtf(var + EPS_);
    gsc_s[tid] = g;
    qp_s[tid] = g * (qv[b * C_ + c] - m) + beta[c];
  }
  const u16* Bbase = XbT + ((size_t)b * L_ + lt * 128) * C_;
  const float* Abase = Q + ((size_t)b * C_ + ct * 128) * C_;
  f32x4 acc[4][4] = {};
  for (int k0 = 0; k0 < C_; k0 += 64) {
    __syncthreads();
#pragma unroll
    for (int ch = 0; ch < 4; ch++) {
      int d = ch * 4096 + tid * 16;
      int row = d >> 7;
      int kb = (d & 127) ^ ((row & 7) << 4);
      gload_lds16(Bbase + (size_t)row * C_ + k0 + (kb >> 1), (char*)lds + d);
    }
    asm volatile("s_waitcnt vmcnt(0)" ::: "memory");
    __syncthreads();
#pragma unroll
    for (int ks = 0; ks < 2; ks++) {
      bf16x8 af[4], bfr[4];
#pragma unroll
      for (int m = 0; m < 4; m++) {
        int row = wr * 64 + m * 16 + (lane & 15);
        int kk = k0 + ks * 32 + ((lane >> 4) << 3);
        float g = gsc_s[row];
        const float* src = Abase + (size_t)row * C_ + kk;
        float4 v0 = *(const float4*)src;
        float4 v1 = *(const float4*)(src + 4);
        bf16x8 a;
        a[0] = (short)f2bf(g * v0.x); a[1] = (short)f2bf(g * v0.y);
        a[2] = (short)f2bf(g * v0.z); a[3] = (short)f2bf(g * v0.w);
        a[4] = (short)f2bf(g * v1.x); a[5] = (short)f2bf(g * v1.y);
        a[6] = (short)f2bf(g * v1.z); a[7] = (short)f2bf(g * v1.w);
        af[m] = a;
      }
#pragma unroll
      for (int n = 0; n < 4; n++) {
        int row = wc * 64 + n * 16 + (lane & 15);
        int kb = ((ks << 6) + ((lane >> 4) << 4)) ^ ((row & 7) << 4);
        bfr[n] = *(const bf16x8*)((const char*)lds + row * 128 + kb);
      }
#pragma unroll
      for (int m = 0; m < 4; m++)
#pragma unroll
        for (int n = 0; n < 4; n++)
          acc[m][n] = __builtin_amdgcn_mfma_f32_16x16x32_bf16(af[m], bfr[n], acc[m][n], 0, 0, 0);
    }
  }
#pragma unroll
  for (int m = 0; m < 4; m++)
#pragma unroll
    for (int n = 0; n < 4; n++) {
      int cl = wr * 64 + m * 16 + ((lane >> 4) << 2);
      int c = ct * 128 + cl;
      int l = lt * 128 + wc * 64 + n * 16 + (lane & 15);
#pragma unroll
      for (int r = 0; r < 4; r++) {
        size_t gi = ((size_t)b * C_ + c + r) * L_ + l;
        out[gi] = acc[m][n][r] + bf2f(Xb[gi]) + qp_s[cl + r];
      }
    }
}

extern "C" void kernel_launch(void* const* d_in, const int* in_sizes, int n_in,
                              void* d_out, int out_size, void* d_ws, size_t ws_size,
                              hipStream_t stream) {
  const float* x       = (const float*)d_in[0];
  const float* g_w     = (const float*)d_in[1];
  const float* g_b     = (const float*)d_in[2];
  const float* theta_w = (const float*)d_in[3];
  const float* theta_b = (const float*)d_in[4];
  const float* phi_w   = (const float*)d_in[5];
  const float* phi_b   = (const float*)d_in[6];
  const float* W_w     = (const float*)d_in[7];
  const float* W_b     = (const float*)d_in[8];
  const float* gamma   = (const float*)d_in[9];
  const float* beta    = (const float*)d_in[10];
  float* out = (float*)d_out;

  float* ws = (float*)d_ws;
  size_t off = 0;
  float* Spart    = ws + off; off += (size_t)SPLITK * B_ * C_ * C_;
  float* S        = ws + off; off += (size_t)B_ * C_ * C_;
  float* spartial = ws + off; off += (size_t)B_ * C_ * 64;
  float* s_       = ws + off; off += B_ * C_;
  float* gwT      = ws + off; off += C_ * OC_;
  float* MT       = ws + off; off += (size_t)B_ * OC_ * OC_;
  float* qv       = ws + off; off += B_ * C_;
  float* Q        = ws + off; off += (size_t)B_ * C_ * C_;
  float* sum1     = ws + off; off += B_ * C_;
  float* sum2     = ws + off; off += B_ * C_;
  u16* Xb  = (u16*)(ws + off); off += (size_t)B_ * C_ * L_ / 2;
  u16* XbT = (u16*)(ws + off); off += (size_t)B_ * C_ * L_ / 2;

  k_cvt<<<dim3(L_ / 64, C_ / 64, B_), 256, 0, stream>>>(x, Xb, XbT, spartial);
  k_xxt<<<dim3(4, SPLITK, B_), 256, 0, stream>>>(Xb, Spart);
  k_sreduce<<<(B_ * C_ * C_) / 256 + (B_ * C_) / 256 + 16, 256, 0, stream>>>(
      Spart, spartial, g_w, S, s_, gwT);
  k_mid1<<<B_ * OC_, 256, 0, stream>>>(S, s_, phi_w, phi_b, gwT, g_b, MT);
  k_mid2stats<<<B_ * C_, 128, 0, stream>>>(MT, W_w, theta_w, theta_b, W_b, S, s_,
                                           Q, qv, sum1, sum2);
  k_out<<<dim3(L_ / 128, C_ / 128, B_), 256, 0, stream>>>(Q, qv, sum1, sum2, gamma,
                                                          beta, XbT, Xb, out);
}